// Round 2
// baseline (539.563 us; speedup 1.0000x reference)
//
#include <hip/hip_runtime.h>
#include <hip/hip_bf16.h>
#include <cstdint>

typedef __attribute__((ext_vector_type(8))) short short8;
typedef __attribute__((ext_vector_type(4))) short short4v;
typedef __attribute__((ext_vector_type(4))) float floatx4;

constexpr int B_ = 2, L_ = 4096, D_ = 1024, H_ = 16, DH = 64, F_ = 4096;
constexpr int M_ = B_ * L_;        // 8192 rows
constexpr int NQKV = 3 * D_;       // 3072
constexpr int VT_GUARD = 512;

// ---------------- workspace layout (bytes) ----------------
constexpr size_t OFF_XB  = 0;                                       // bf16 [M][D]
constexpr size_t OFF_WCT = OFF_XB  + (size_t)M_ * D_ * 2;           // bf16 [3072][1024]
constexpr size_t OFF_W1T = OFF_WCT + (size_t)NQKV * D_ * 2;         // bf16 [4096][1024]
constexpr size_t OFF_W2T = OFF_W1T + (size_t)F_ * D_ * 2;           // bf16 [1024][4096]
constexpr size_t OFF_QKV = OFF_W2T + (size_t)D_ * F_ * 2;           // bf16 [M][3072]
constexpr size_t OFF_VT  = OFF_QKV + (size_t)M_ * NQKV * 2;
constexpr size_t OFF_ATT = OFF_VT  + ((size_t)B_*H_*DH*L_ + 2*VT_GUARD) * 2;
constexpr size_t OFF_HB  = OFF_ATT + (size_t)M_ * D_ * 2;
constexpr size_t OFF_MID = OFF_HB  + (size_t)M_ * D_ * 2;           // bf16 [M][F]

static __device__ __forceinline__ float b2f(unsigned short u) {
    union { unsigned int i; float f; } v; v.i = ((unsigned int)u) << 16; return v.f;
}

static __device__ __forceinline__ void gload16(const void* g, void* l) {
    __builtin_amdgcn_global_load_lds(
        (const __attribute__((address_space(1))) uint32_t*)g,
        (__attribute__((address_space(3))) uint32_t*)l, 16, 0, 0);
}

static __device__ __forceinline__ void bar() {
    asm volatile("" ::: "memory");
    __builtin_amdgcn_s_barrier();
    asm volatile("" ::: "memory");
}
static __device__ __forceinline__ void waitlgk0() {
    asm volatile("s_waitcnt lgkmcnt(0)" ::: "memory");
    __builtin_amdgcn_sched_barrier(0);
}
template<int N> static __device__ __forceinline__ void waitvm() {
    if constexpr (N == 3)      asm volatile("s_waitcnt vmcnt(3)" ::: "memory");
    else if constexpr (N == 4) asm volatile("s_waitcnt vmcnt(4)" ::: "memory");
    else                       asm volatile("s_waitcnt vmcnt(0)" ::: "memory");
}

// ---------------- f32 -> bf16 convert (x) ----------------
__global__ __launch_bounds__(256) void k_cvt_x(const float* __restrict__ x,
                                               __hip_bfloat16* __restrict__ xb) {
    int i = (blockIdx.x * 256 + threadIdx.x) * 8;
    float4 a = *(const float4*)(x + i);
    float4 b = *(const float4*)(x + i + 4);
    alignas(16) __hip_bfloat16 t[8];
    t[0] = __float2bfloat16(a.x); t[1] = __float2bfloat16(a.y);
    t[2] = __float2bfloat16(a.z); t[3] = __float2bfloat16(a.w);
    t[4] = __float2bfloat16(b.x); t[5] = __float2bfloat16(b.y);
    t[6] = __float2bfloat16(b.z); t[7] = __float2bfloat16(b.w);
    *(uint4*)(xb + i) = *(const uint4*)t;
}

// ---------------- transpose+convert: in [R][C] f32 -> out [C][R] bf16 ----------------
__global__ __launch_bounds__(256) void k_tcvt(const float* __restrict__ in,
                                              __hip_bfloat16* __restrict__ out,
                                              int R, int C) {
    __shared__ float t[64][65];
    int tx = threadIdx.x & 63, ty4 = threadIdx.x >> 6;
    int c0 = blockIdx.x * 64, r0 = blockIdx.y * 64;
#pragma unroll
    for (int i = 0; i < 16; i++) {
        int r = ty4 + i * 4;
        t[r][tx] = in[(size_t)(r0 + r) * C + c0 + tx];
    }
    __syncthreads();
#pragma unroll
    for (int i = 0; i < 16; i++) {
        int r = ty4 + i * 4;
        out[(size_t)(c0 + r) * R + r0 + tx] = __float2bfloat16(t[tx][r]);
    }
}

// ---------------- V transpose ----------------
__global__ __launch_bounds__(256) void k_vtrans(const __hip_bfloat16* __restrict__ qkv,
                                                __hip_bfloat16* __restrict__ vtg) {
    __shared__ __hip_bfloat16 t[64][72];
    int tx = threadIdx.x & 63, ty4 = threadIdx.x >> 6;
    int bh = blockIdx.y, b = bh >> 4, h = bh & 15;
    int j0 = blockIdx.x * 64;
#pragma unroll
    for (int i = 0; i < 16; i++) {
        int j = ty4 + i * 4;
        t[j][tx] = qkv[(size_t)(b * L_ + j0 + j) * NQKV + 2 * D_ + h * DH + tx];
    }
    __syncthreads();
#pragma unroll
    for (int i = 0; i < 16; i++) {
        int d = ty4 + i * 4;
        vtg[(long)(bh * DH + d) * L_ + j0 + tx] = t[tx][d];
    }
}

// ---------------- 256-tile 4-phase GEMM ----------------
// C[8192][NTOT] = A[8192][KTOT] * BT[NTOT][KTOT]^T, 8 waves (2M x 4N), per-wave 128 x NF*16.
// BK=64 split into two K=32 units; double-buffered LDS; counted vmcnt; setprio around MFMA.
template<int NF, int EPI, int NTOT, int KTOT>
__global__ __launch_bounds__(512, 2)
void k_gemm8(const __hip_bfloat16* __restrict__ A, const __hip_bfloat16* __restrict__ BT,
             const float* __restrict__ b0p, const float* __restrict__ b1p,
             const float* __restrict__ b2p,
             __hip_bfloat16* __restrict__ obf, float* __restrict__ of32,
             const __hip_bfloat16* __restrict__ hres) {
    constexpr int BN = NF * 64;
    constexpr int BLOADS = NF / 2;          // B gloads per thread per unit
    constexpr int UU = 2 + BLOADS;          // loads per unit per thread
    constexpr int KT = KTOT / 64;
    constexpr int MB = 32;                  // 8192/256

    __shared__ __hip_bfloat16 As[2][2][256 * 32];
    __shared__ __hip_bfloat16 Bs[2][2][BN * 32];

    const int tid = threadIdx.x, wave = tid >> 6, lane = tid & 63;
    const int lo = lane & 15, hi = lane >> 4;
    const int wm = wave >> 2, wn = wave & 3;

    // bijective XCD swizzle (grid % 8 == 0 for all instantiations)
    const int nwg = gridDim.x, q = nwg >> 3;
    const int bid = blockIdx.x;
    const int swz = (bid & 7) * q + (bid >> 3);
    const int bm = swz & (MB - 1), bn = swz >> 5;
    const size_t m0 = (size_t)bm * 256, n0 = (size_t)bn * BN;

    // staging thread geometry: row = tid>>2 (+128/sweep), chunk fixed per thread
    const int rowT = tid >> 2;
    const int chunkT = (((tid & 3) ^ ((tid >> 3) & 3))) * 8;
    const __hip_bfloat16* aG = A  + (m0 + rowT) * (size_t)KTOT + chunkT;
    const __hip_bfloat16* bG = BT + (n0 + rowT) * (size_t)KTOT + chunkT;

    // fragment read offsets (elements): row*32 + swizzled 16B slot
    const int swz16 = (hi ^ ((lo >> 1) & 3)) * 8;
    const int aOff = (wm * 128 + lo) * 32 + swz16;
    const int bOff = (wn * (NF * 16) + lo) * 32 + swz16;

    floatx4 acc[8][NF] = {};

#define STAGE_A(nb2, kh, kcol)                                              \
    _Pragma("unroll")                                                       \
    for (int s = 0; s < 2; ++s)                                             \
        gload16(aG + (size_t)s * 128 * KTOT + (kcol),                       \
                &As[nb2][kh][(s * 512 + wave * 64) * 8]);
#define STAGE_B(nb2, kh, kcol)                                              \
    _Pragma("unroll")                                                       \
    for (int s = 0; s < BLOADS; ++s)                                        \
        gload16(bG + (size_t)s * 128 * KTOT + (kcol),                       \
                &Bs[nb2][kh][(s * 512 + wave * 64) * 8]);

    // prologue: stage both units of tile 0 into buffer 0
    STAGE_A(0, 0, 0); STAGE_B(0, 0, 0);
    STAGE_A(0, 1, 32); STAGE_B(0, 1, 32);
    waitvm<UU>();
    bar();

#pragma unroll 2
    for (int kt = 0; kt < KT; ++kt) {
        const int cur = kt & 1, nxt = cur ^ 1;
        const int kn = ((kt + 1 < KT) ? (kt + 1) : kt) * 64;
        short8 bfr[NF], afr[4];
        const __hip_bfloat16* aL0 = &As[cur][0][0];
        const __hip_bfloat16* bL0 = &Bs[cur][0][0];
        const __hip_bfloat16* aL1 = &As[cur][1][0];
        const __hip_bfloat16* bL1 = &Bs[cur][1][0];

        // ---- phase 1: kh0, m-half 0 ----
#pragma unroll
        for (int nf = 0; nf < NF; ++nf) bfr[nf] = *(const short8*)(bL0 + bOff + nf * 512);
#pragma unroll
        for (int mf = 0; mf < 4; ++mf) afr[mf] = *(const short8*)(aL0 + aOff + mf * 512);
        STAGE_A(nxt, 0, kn); STAGE_B(nxt, 0, kn);
        bar(); waitlgk0();
        __builtin_amdgcn_s_setprio(1);
#pragma unroll
        for (int mf = 0; mf < 4; ++mf)
#pragma unroll
            for (int nf = 0; nf < NF; ++nf)
                acc[mf][nf] = __builtin_amdgcn_mfma_f32_16x16x32_bf16(afr[mf], bfr[nf], acc[mf][nf], 0, 0, 0);
        __builtin_amdgcn_s_setprio(0);
        bar();

        // ---- phase 2: kh0, m-half 1 ----
#pragma unroll
        for (int mf = 0; mf < 4; ++mf) afr[mf] = *(const short8*)(aL0 + aOff + (4 + mf) * 512);
        bar(); waitlgk0();
        __builtin_amdgcn_s_setprio(1);
#pragma unroll
        for (int mf = 0; mf < 4; ++mf)
#pragma unroll
            for (int nf = 0; nf < NF; ++nf)
                acc[4 + mf][nf] = __builtin_amdgcn_mfma_f32_16x16x32_bf16(afr[mf], bfr[nf], acc[4 + mf][nf], 0, 0, 0);
        __builtin_amdgcn_s_setprio(0);
        waitvm<UU>();
        bar();

        // ---- phase 3: kh1, m-half 0 ----
#pragma unroll
        for (int nf = 0; nf < NF; ++nf) bfr[nf] = *(const short8*)(bL1 + bOff + nf * 512);
#pragma unroll
        for (int mf = 0; mf < 4; ++mf) afr[mf] = *(const short8*)(aL1 + aOff + mf * 512);
        STAGE_A(nxt, 1, kn + 32); STAGE_B(nxt, 1, kn + 32);
        bar(); waitlgk0();
        __builtin_amdgcn_s_setprio(1);
#pragma unroll
        for (int mf = 0; mf < 4; ++mf)
#pragma unroll
            for (int nf = 0; nf < NF; ++nf)
                acc[mf][nf] = __builtin_amdgcn_mfma_f32_16x16x32_bf16(afr[mf], bfr[nf], acc[mf][nf], 0, 0, 0);
        __builtin_amdgcn_s_setprio(0);
        bar();

        // ---- phase 4: kh1, m-half 1 ----
#pragma unroll
        for (int mf = 0; mf < 4; ++mf) afr[mf] = *(const short8*)(aL1 + aOff + (4 + mf) * 512);
        bar(); waitlgk0();
        __builtin_amdgcn_s_setprio(1);
#pragma unroll
        for (int mf = 0; mf < 4; ++mf)
#pragma unroll
            for (int nf = 0; nf < NF; ++nf)
                acc[4 + mf][nf] = __builtin_amdgcn_mfma_f32_16x16x32_bf16(afr[mf], bfr[nf], acc[4 + mf][nf], 0, 0, 0);
        __builtin_amdgcn_s_setprio(0);
        waitvm<UU>();
        bar();
    }
#undef STAGE_A
#undef STAGE_B

    // ---- epilogue ----
#pragma unroll
    for (int mf = 0; mf < 8; ++mf) {
        const int row = (int)m0 + wm * 128 + mf * 16 + hi * 4;
#pragma unroll
        for (int nf = 0; nf < NF; ++nf) {
            const int col = (int)n0 + wn * (NF * 16) + nf * 16 + lo;
#pragma unroll
            for (int r = 0; r < 4; ++r) {
                float v = acc[mf][nf][r];
                const size_t ro = (size_t)(row + r);
                if (EPI == 0) {
                    float bia = (col < 1024) ? b0p[col]
                              : (col < 2048 ? b1p[col - 1024] : b2p[col - 2048]);
                    obf[ro * NQKV + col] = __float2bfloat16(v + bia);
                } else if (EPI == 1) {
                    v += b0p[col];
                    v = 0.5f * v * (1.0f + erff(v * 0.70710678118654752440f));
                    obf[ro * F_ + col] = __float2bfloat16(v);
                } else {
                    v += b0p[col];
                    v += b2f(*(const unsigned short*)&hres[ro * D_ + col]);
                    of32[ro * D_ + col] = v;
                }
            }
        }
    }
}

// ---------------- sliding-window attention (unchanged, verified) ----------------
__global__ __launch_bounds__(256, 2)
void k_attn(const __hip_bfloat16* __restrict__ qkv, const float* __restrict__ mask,
            const __hip_bfloat16* __restrict__ vtg, __hip_bfloat16* __restrict__ attnb) {
    constexpr int PS = 296;
    __shared__ __hip_bfloat16 P[4][16 * PS];
    const int tid = threadIdx.x, wave = tid >> 6, lane = tid & 63;
    const int bh = blockIdx.y, b = bh >> 4, h = bh & 15;
    const int q0 = blockIdx.x * 64 + wave * 16;
    const int lo = lane & 15, hi = lane >> 4;

    short8 qf0, qf1;
    {
        const __hip_bfloat16* qb = qkv + (size_t)(b * L_ + q0 + lo) * NQKV + h * DH + hi * 8;
        qf0 = *(const short8*)qb;
        qf1 = *(const short8*)(qb + 32);
    }

    floatx4 sc[17];
    const __hip_bfloat16* kcol = qkv + (size_t)b * L_ * NQKV + D_ + h * DH + hi * 8;
#pragma unroll
    for (int t = 0; t < 17; t++) {
        int jg = q0 - 128 + t * 16 + lo;
        int jc = jg < 0 ? 0 : (jg >= L_ ? L_ - 1 : jg);
        const __hip_bfloat16* kb = kcol + (size_t)jc * NQKV;
        short8 kf0 = *(const short8*)kb;
        short8 kf1 = *(const short8*)(kb + 32);
        floatx4 a = {};
        a = __builtin_amdgcn_mfma_f32_16x16x32_bf16(qf0, kf0, a, 0, 0, 0);
        a = __builtin_amdgcn_mfma_f32_16x16x32_bf16(qf1, kf1, a, 0, 0, 0);
        float mval = mask[b * L_ + jc];
        bool jok = (jg >= 0) && (jg < L_) && (mval == 0.0f);
#pragma unroll
        for (int r = 0; r < 4; r++) {
            int qi = q0 + hi * 4 + r;
            bool ok = jok && (jg >= qi - 128) && (jg <= qi + 128);
            a[r] = ok ? a[r] * 0.125f : -1e9f;
        }
        sc[t] = a;
    }

#pragma unroll
    for (int r = 0; r < 4; r++) {
        float m = -3e38f;
#pragma unroll
        for (int t = 0; t < 17; t++) m = fmaxf(m, sc[t][r]);
        m = fmaxf(m, __shfl_xor(m, 1));
        m = fmaxf(m, __shfl_xor(m, 2));
        m = fmaxf(m, __shfl_xor(m, 4));
        m = fmaxf(m, __shfl_xor(m, 8));
        float s = 0.0f;
#pragma unroll
        for (int t = 0; t < 17; t++) { float e = __expf(sc[t][r] - m); sc[t][r] = e; s += e; }
        s += __shfl_xor(s, 1); s += __shfl_xor(s, 2);
        s += __shfl_xor(s, 4); s += __shfl_xor(s, 8);
        float inv = 1.0f / s;
#pragma unroll
        for (int t = 0; t < 17; t++) sc[t][r] *= inv;
    }

    __hip_bfloat16* Pw = &P[wave][0];
#pragma unroll
    for (int t = 0; t < 17; t++)
#pragma unroll
        for (int r = 0; r < 4; r++)
            Pw[(hi * 4 + r) * PS + t * 16 + lo] = __float2bfloat16(sc[t][r]);
    {
        int zr = lane >> 2, zc = 272 + (lane & 3) * 4;
        __hip_bfloat16 z = __float2bfloat16(0.0f);
#pragma unroll
        for (int i = 0; i < 4; i++) Pw[zr * PS + zc + i] = z;
    }

    floatx4 o[4] = {};
#pragma unroll
    for (int st = 0; st < 9; st++) {
        short8 pa = *(const short8*)(Pw + lo * PS + st * 32 + hi * 8);
        int jb = q0 - 128 + st * 32 + hi * 8;
#pragma unroll
        for (int dt = 0; dt < 4; dt++) {
            const __hip_bfloat16* vb = vtg + (long)(bh * DH + dt * 16 + lo) * L_ + jb;
            short8 vf = *(const short8*)vb;
            o[dt] = __builtin_amdgcn_mfma_f32_16x16x32_bf16(pa, vf, o[dt], 0, 0, 0);
        }
    }

#pragma unroll
    for (int dt = 0; dt < 4; dt++)
#pragma unroll
        for (int r = 0; r < 4; r++) {
            int row = q0 + hi * 4 + r;
            attnb[(size_t)(b * L_ + row) * D_ + h * DH + dt * 16 + lo] =
                __float2bfloat16(o[dt][r]);
        }
}

// ---------------- residual + LayerNorm ----------------
__global__ __launch_bounds__(256)
void k_ln(const float* __restrict__ x, const __hip_bfloat16* __restrict__ attnb,
          const float* __restrict__ g, const float* __restrict__ bt,
          __hip_bfloat16* __restrict__ hb) {
    const int row = blockIdx.x, tid = threadIdx.x;
    const int c4 = tid * 4;
    float4 xv = *(const float4*)(x + (size_t)row * D_ + c4);
    short4v av = *(const short4v*)(attnb + (size_t)row * D_ + c4);
    float h0 = xv.x + b2f((unsigned short)av[0]);
    float h1 = xv.y + b2f((unsigned short)av[1]);
    float h2 = xv.z + b2f((unsigned short)av[2]);
    float h3 = xv.w + b2f((unsigned short)av[3]);
    float s = h0 + h1 + h2 + h3;
    float q = h0 * h0 + h1 * h1 + h2 * h2 + h3 * h3;
#pragma unroll
    for (int off = 32; off > 0; off >>= 1) {
        s += __shfl_down(s, off);
        q += __shfl_down(q, off);
    }
    __shared__ float red[8];
    int wave = tid >> 6, lane = tid & 63;
    if (lane == 0) { red[wave] = s; red[4 + wave] = q; }
    __syncthreads();
    s = red[0] + red[1] + red[2] + red[3];
    q = red[4] + red[5] + red[6] + red[7];
    float mu = s * (1.0f / D_);
    float var = q * (1.0f / D_) - mu * mu;
    float inv = rsqrtf(var + 1e-5f);
    float4 gv = *(const float4*)(g + c4);
    float4 bv = *(const float4*)(bt + c4);
    alignas(8) __hip_bfloat16 ov[4];
    ov[0] = __float2bfloat16((h0 - mu) * inv * gv.x + bv.x);
    ov[1] = __float2bfloat16((h1 - mu) * inv * gv.y + bv.y);
    ov[2] = __float2bfloat16((h2 - mu) * inv * gv.z + bv.z);
    ov[3] = __float2bfloat16((h3 - mu) * inv * gv.w + bv.w);
    *(short4v*)(hb + (size_t)row * D_ + c4) = *(const short4v*)ov;
}

// ---------------- launch ----------------
extern "C" void kernel_launch(void* const* d_in, const int* in_sizes, int n_in,
                              void* d_out, int out_size, void* d_ws, size_t ws_size,
                              hipStream_t stream) {
    const float* x    = (const float*)d_in[0];
    const float* mask = (const float*)d_in[1];
    const float* Wq   = (const float*)d_in[2];
    const float* bq   = (const float*)d_in[3];
    const float* Wk   = (const float*)d_in[4];
    const float* bk   = (const float*)d_in[5];
    const float* Wv   = (const float*)d_in[6];
    const float* bv   = (const float*)d_in[7];
    const float* ln_g = (const float*)d_in[8];
    const float* ln_b = (const float*)d_in[9];
    const float* W1   = (const float*)d_in[10];
    const float* b1   = (const float*)d_in[11];
    const float* W2   = (const float*)d_in[12];
    const float* b2   = (const float*)d_in[13];
    float* out = (float*)d_out;
    char* ws = (char*)d_ws;

    __hip_bfloat16* xb   = (__hip_bfloat16*)(ws + OFF_XB);
    __hip_bfloat16* wct  = (__hip_bfloat16*)(ws + OFF_WCT);
    __hip_bfloat16* w1t  = (__hip_bfloat16*)(ws + OFF_W1T);
    __hip_bfloat16* w2t  = (__hip_bfloat16*)(ws + OFF_W2T);
    __hip_bfloat16* qkvb = (__hip_bfloat16*)(ws + OFF_QKV);
    __hip_bfloat16* vtg  = (__hip_bfloat16*)(ws + OFF_VT) + VT_GUARD;
    __hip_bfloat16* attb = (__hip_bfloat16*)(ws + OFF_ATT);
    __hip_bfloat16* hb   = (__hip_bfloat16*)(ws + OFF_HB);
    __hip_bfloat16* midb = (__hip_bfloat16*)(ws + OFF_MID);

    // input conversions
    k_cvt_x<<<(M_ * D_) / 2048, 256, 0, stream>>>(x, xb);
    k_tcvt<<<dim3(D_ / 64, D_ / 64), 256, 0, stream>>>(Wq, wct,                   D_, D_);
    k_tcvt<<<dim3(D_ / 64, D_ / 64), 256, 0, stream>>>(Wk, wct + 1024 * 1024,     D_, D_);
    k_tcvt<<<dim3(D_ / 64, D_ / 64), 256, 0, stream>>>(Wv, wct + 2 * 1024 * 1024, D_, D_);
    k_tcvt<<<dim3(F_ / 64, D_ / 64), 256, 0, stream>>>(W1, w1t, D_, F_);
    k_tcvt<<<dim3(D_ / 64, F_ / 64), 256, 0, stream>>>(W2, w2t, F_, D_);

    // fused QKV projection: grid = 32 * 12 = 384
    k_gemm8<4, 0, NQKV, D_><<<32 * (NQKV / 256), 512, 0, stream>>>(
        xb, wct, bq, bk, bv, qkvb, nullptr, nullptr);

    // V transpose, attention
    k_vtrans<<<dim3(L_ / 64, B_ * H_), 256, 0, stream>>>(qkvb, vtg);
    k_attn<<<dim3(L_ / 64, B_ * H_), 256, 0, stream>>>(qkvb, mask, vtg, attb);

    // residual + LN
    k_ln<<<M_, 256, 0, stream>>>(x, attb, ln_g, ln_b, hb);

    // MLP: grid 32*16 = 512 ; grid 32*8 = 256
    k_gemm8<4, 1, F_, D_><<<32 * (F_ / 256), 512, 0, stream>>>(
        hb, w1t, b1, nullptr, nullptr, midb, nullptr, nullptr);
    k_gemm8<2, 2, D_, F_><<<32 * (D_ / 128), 512, 0, stream>>>(
        midb, w2t, b2, nullptr, nullptr, nullptr, out, hb);
}